// Round 15
// baseline (429.829 us; speedup 1.0000x reference)
//
#include <hip/hip_runtime.h>
#include <hip/hip_bf16.h>

typedef __attribute__((ext_vector_type(8))) short short8;
typedef __attribute__((ext_vector_type(4))) float f32x4;

// z: [64, 256, 32, 32] f32 ; codebook: [512, 256] f32
// d_out f32: [z_q_st (16777216) | indices (65536) | loss (1)]
#define C_DIM   256
#define K_CODES 512
#define N_POS   65536
#define OUT0_ELEMS 16777216
#define OUT1_ELEMS 65536
#define W_AMB 2.0e-3f     // screen ordering error ~2.5e-4; 8x margin (R14-proven)

// ---------------------------------------------------------------------------
// codebook -> bf16 hi/lo rows
// ---------------------------------------------------------------------------
__global__ __launch_bounds__(256) void vq_convcb_kernel(const float* __restrict__ cb,
    __hip_bfloat16* __restrict__ Ch, __hip_bfloat16* __restrict__ Cl)
{
    const int i = blockIdx.x * 256 + threadIdx.x;
    float v = cb[i];
    __hip_bfloat16 h = __float2bfloat16(v);
    __hip_bfloat16 l = __float2bfloat16(v - __bfloat162float(h));
    Ch[i] = h; Cl[i] = l;
}

// ---------------------------------------------------------------------------
// cc[k] = sum_c cb[k][c]^2, numpy pairwise order (proven)
// ---------------------------------------------------------------------------
__global__ __launch_bounds__(256) void vq_cc_kernel(const float* __restrict__ cb,
                                                    float* __restrict__ cc)
{
    const int k = blockIdx.x * 256 + threadIdx.x;
    const float* row = cb + (size_t)k * C_DIM;
    float s1[8], s2[8];
    #pragma unroll
    for (int j = 0; j < 8; ++j) { s1[j] = 0.f; s2[j] = 0.f; }
    for (int c8 = 0; c8 < 16; ++c8)
        #pragma unroll
        for (int j = 0; j < 8; ++j) {
            float v = row[c8 * 8 + j];
            s1[j] = __fadd_rn(s1[j], __fmul_rn(v, v));
        }
    for (int c8 = 16; c8 < 32; ++c8)
        #pragma unroll
        for (int j = 0; j < 8; ++j) {
            float v = row[c8 * 8 + j];
            s2[j] = __fadd_rn(s2[j], __fmul_rn(v, v));
        }
    float b1 = __fadd_rn(__fadd_rn(__fadd_rn(s1[0], s1[1]), __fadd_rn(s1[2], s1[3])),
                         __fadd_rn(__fadd_rn(s1[4], s1[5]), __fadd_rn(s1[6], s1[7])));
    float b2 = __fadd_rn(__fadd_rn(__fadd_rn(s2[0], s2[1]), __fadd_rn(s2[2], s2[3])),
                         __fadd_rn(__fadd_rn(s2[4], s2[5]), __fadd_rn(s2[6], s2[7])));
    cc[k] = __fadd_rn(b1, b2);
}

// ---------------------------------------------------------------------------
// z -> Zh/Zl bf16 in [pos][c] layout (R12-proven pattern, extended with lo)
// ---------------------------------------------------------------------------
__global__ __launch_bounds__(256) void vq_splitz_kernel(const float* __restrict__ z,
    __hip_bfloat16* __restrict__ Zh, __hip_bfloat16* __restrict__ Zl)
{
    const int tid = threadIdx.x;
    const int p   = blockIdx.x * 32 + (tid >> 3);
    const int c8  = tid & 7;
    const float* zb = z + ((size_t)(p >> 10) << 18) + (p & 1023);
    __hip_bfloat16* oh = Zh + (size_t)p * C_DIM;
    __hip_bfloat16* ol = Zl + (size_t)p * C_DIM;
    #pragma unroll
    for (int q = 0; q < 4; ++q) {
        const int c0 = q * 64 + c8 * 8;
        short8 ph, pl;
        #pragma unroll
        for (int j = 0; j < 8; ++j) {
            float v = zb[(size_t)(c0 + j) << 10];
            __hip_bfloat16 h = __float2bfloat16(v);
            __hip_bfloat16 l = __float2bfloat16(v - __bfloat162float(h));
            ph[j] = *reinterpret_cast<short*>(&h);
            pl[j] = *reinterpret_cast<short*>(&l);
        }
        *reinterpret_cast<short8*>(oh + c0) = ph;
        *reinterpret_cast<short8*>(ol + c0) = pl;
    }
}

// ---------------------------------------------------------------------------
// Screen: block = 64 pos x all 512 codes. 3-term split MFMA (zh.ch + zh.cl +
// zl.ch) in 3 sequential passes (one A-frag set live -> low VGPR). Operands
// from global bf16 (no LDS z, no in-loop converts). Tracks per-pos top-2 of
// screen d = cc - 2*dot (R14-proven epilogue). Writes out1 = (float)best_c
// and gapd = second - best. LDS only 3 KB of reduce buffers.
// ---------------------------------------------------------------------------
__global__ __launch_bounds__(256) void vq_screen_kernel(
    const __hip_bfloat16* __restrict__ Zh, const __hip_bfloat16* __restrict__ Zl,
    const __hip_bfloat16* __restrict__ Ch, const __hip_bfloat16* __restrict__ Cl,
    const float* __restrict__ ccv, float* __restrict__ out1f,
    float* __restrict__ gapd)
{
    const int pt   = blockIdx.x;          // 0..1023 (64-pos tile)
    const int tid  = threadIdx.x;
    const int lane = tid & 63;
    const int w    = tid >> 6;
    const int r16  = lane & 15;
    const int kg   = lane >> 4;

    __shared__ float wb[4][64];
    __shared__ float wsec[4][64];
    __shared__ int   wc[4][64];

    f32x4 acc[2][4][4];
    #pragma unroll
    for (int rd = 0; rd < 2; ++rd)
        #pragma unroll
        for (int mf = 0; mf < 4; ++mf)
            #pragma unroll
            for (int nf = 0; nf < 4; ++nf)
                acc[rd][mf][nf] = (f32x4){0.f, 0.f, 0.f, 0.f};

    // 3 passes: (Zh,Ch), (Zh,Cl), (Zl,Ch)
    #pragma unroll 1
    for (int t = 0; t < 3; ++t) {
        const __hip_bfloat16* A = (t == 2) ? Zl : Zh;
        const __hip_bfloat16* B = (t == 1) ? Cl : Ch;
        for (int kk = 0; kk < 8; ++kk) {
            const int cc0 = kk * 32 + kg * 8;
            short8 a[4];
            #pragma unroll
            for (int mf = 0; mf < 4; ++mf) {
                const int pos = (pt << 6) + (mf << 4) + r16;
                a[mf] = *reinterpret_cast<const short8*>(A + (size_t)pos * C_DIM + cc0);
            }
            #pragma unroll
            for (int rd = 0; rd < 2; ++rd) {
                #pragma unroll
                for (int nf = 0; nf < 4; ++nf) {
                    const int code = rd * 256 + w * 64 + nf * 16 + r16;
                    short8 bf = *reinterpret_cast<const short8*>(B + (size_t)code * C_DIM + cc0);
                    #pragma unroll
                    for (int mf = 0; mf < 4; ++mf)
                        acc[rd][mf][nf] = __builtin_amdgcn_mfma_f32_16x16x32_bf16(a[mf], bf, acc[rd][mf][nf], 0, 0, 0);
                }
            }
        }
    }

    // per-lane top-2 (slots s = mf*4+r; ascending code within lane)
    float tb[16], ts[16];
    int   tc[16];
    #pragma unroll
    for (int s = 0; s < 16; ++s) { tb[s] = 3.4e38f; ts[s] = 3.4e38f; tc[s] = 0; }

    #pragma unroll
    for (int rd = 0; rd < 2; ++rd) {
        #pragma unroll
        for (int nf = 0; nf < 4; ++nf) {
            const int code = rd * 256 + w * 64 + nf * 16 + r16;
            const float cck = ccv[code];
            #pragma unroll
            for (int mf = 0; mf < 4; ++mf) {
                #pragma unroll
                for (int r = 0; r < 4; ++r) {
                    const int s = mf * 4 + r;
                    float d = __builtin_fmaf(-2.0f, acc[rd][mf][nf][r], cck);
                    if (d < tb[s]) { ts[s] = tb[s]; tb[s] = d; tc[s] = code; }
                    else if (d < ts[s]) { ts[s] = d; }
                }
            }
        }
    }

    // cross-lane (within 16-lane r16 group) top-2 combine — R14-proven
    #pragma unroll
    for (int s = 0; s < 16; ++s) {
        #pragma unroll
        for (int m = 1; m <= 8; m <<= 1) {
            float ob = __shfl_xor(tb[s], m, 64);
            int   oc = __shfl_xor(tc[s], m, 64);
            float os = __shfl_xor(ts[s], m, 64);
            if (ob < tb[s] || (ob == tb[s] && oc < tc[s])) {
                ts[s] = fminf(tb[s], os); tb[s] = ob; tc[s] = oc;
            } else {
                ts[s] = fminf(ts[s], ob);
            }
        }
    }
    if (r16 == 0) {
        #pragma unroll
        for (int mf = 0; mf < 4; ++mf)
            #pragma unroll
            for (int r = 0; r < 4; ++r) {
                const int pl = mf * 16 + kg * 4 + r;
                wb[w][pl]   = tb[mf * 4 + r];
                wc[w][pl]   = tc[mf * 4 + r];
                wsec[w][pl] = ts[mf * 4 + r];
            }
    }
    __syncthreads();

    if (w == 0) {
        float B = wb[0][lane]; int C = wc[0][lane]; float S = wsec[0][lane];
        #pragma unroll
        for (int ww = 1; ww < 4; ++ww) {
            float ob = wb[ww][lane]; int oc = wc[ww][lane]; float os = wsec[ww][lane];
            if (ob < B || (ob == B && oc < C)) { S = fminf(B, os); B = ob; C = oc; }
            else { S = fminf(S, ob); }
        }
        const int P = (pt << 6) + lane;
        out1f[P] = (float)C;        // index as float (final unless ambiguous)
        gapd[P]  = S - B;           // gap; overwritten with d_min by finalize/amb
    }
}

// ---------------------------------------------------------------------------
// Finalize: per pos. gap > W -> one np-exact chain for the screen winner
// (inline np-pairwise zz from the same coalesced z reads); writes d into the
// gap slot. gap <= W -> leave for amb kernel. Proven chain numerics.
// ---------------------------------------------------------------------------
__global__ __launch_bounds__(256) void vq_finalize_kernel(
    const float* __restrict__ z, const float* __restrict__ cb,
    const float* __restrict__ ccv, const float* __restrict__ out1f,
    float* __restrict__ gapd)
{
    const int pos = blockIdx.x * 256 + threadIdx.x;
    if (gapd[pos] <= W_AMB) return;          // ambiguous: amb kernel resolves

    const int code = (int)out1f[pos];
    const float* zr = z + ((size_t)(pos >> 10) << 18) + (pos & 1023);
    const float4* crow4 = reinterpret_cast<const float4*>(cb + ((size_t)code << 8));

    float s1[8], s2[8];
    #pragma unroll
    for (int j = 0; j < 8; ++j) { s1[j] = 0.f; s2[j] = 0.f; }
    float a0 = 0.f;
    for (int c8 = 0; c8 < 16; ++c8) {
        float4 cv0 = crow4[c8 * 2];
        float4 cv1 = crow4[c8 * 2 + 1];
        const float cv[8] = {cv0.x, cv0.y, cv0.z, cv0.w, cv1.x, cv1.y, cv1.z, cv1.w};
        #pragma unroll
        for (int j = 0; j < 8; ++j) {
            float v = zr[(size_t)(c8 * 8 + j) << 10];
            s1[j] = __fadd_rn(s1[j], __fmul_rn(v, v));
            a0 = __builtin_fmaf(v, cv[j], a0);
        }
    }
    for (int c8 = 16; c8 < 32; ++c8) {
        float4 cv0 = crow4[c8 * 2];
        float4 cv1 = crow4[c8 * 2 + 1];
        const float cv[8] = {cv0.x, cv0.y, cv0.z, cv0.w, cv1.x, cv1.y, cv1.z, cv1.w};
        #pragma unroll
        for (int j = 0; j < 8; ++j) {
            float v = zr[(size_t)(c8 * 8 + j) << 10];
            s2[j] = __fadd_rn(s2[j], __fmul_rn(v, v));
            a0 = __builtin_fmaf(v, cv[j], a0);
        }
    }
    float b1 = __fadd_rn(__fadd_rn(__fadd_rn(s1[0], s1[1]), __fadd_rn(s1[2], s1[3])),
                         __fadd_rn(__fadd_rn(s1[4], s1[5]), __fadd_rn(s1[6], s1[7])));
    float b2 = __fadd_rn(__fadd_rn(__fadd_rn(s2[0], s2[1]), __fadd_rn(s2[2], s2[3])),
                         __fadd_rn(__fadd_rn(s2[4], s2[5]), __fadd_rn(s2[6], s2[7])));
    float zz = __fadd_rn(b1, b2);
    float d = __fadd_rn(__fsub_rn(zz, __fmul_rn(2.0f, a0)), ccv[code]);
    gapd[pos] = d;                           // slot now holds d_min
}

// ---------------------------------------------------------------------------
// Ambiguous positions (gap <= W): full 512-code np-exact argmin per pos,
// block-wide (2 chains/thread, z row in LDS, inline np-zz, deterministic
// first-min reduce). Scans its 256-pos slice — no list, no atomics.
// ---------------------------------------------------------------------------
__global__ __launch_bounds__(256) void vq_amb_kernel(
    const float* __restrict__ z, const float* __restrict__ cb,
    const float* __restrict__ ccv, float* __restrict__ out1f,
    float* __restrict__ gapd)
{
    const int tid = threadIdx.x;
    const int base = blockIdx.x * 256;
    __shared__ float zrow[256];
    __shared__ float sd[256];
    __shared__ int   sc[256];

    for (int e = 0; e < 256; ++e) {
        const int pos = base + e;
        if (gapd[pos] > W_AMB) continue;     // uniform (all threads read same value)

        zrow[tid] = z[((size_t)(pos >> 10) << 18) + ((size_t)tid << 10) + (pos & 1023)];
        __syncthreads();

        // zz inline, np-pairwise (broadcast LDS reads; all threads same value)
        float s1[8], s2[8];
        #pragma unroll
        for (int j = 0; j < 8; ++j) { s1[j] = 0.f; s2[j] = 0.f; }
        for (int c8 = 0; c8 < 16; ++c8)
            #pragma unroll
            for (int j = 0; j < 8; ++j) {
                float v = zrow[c8 * 8 + j];
                s1[j] = __fadd_rn(s1[j], __fmul_rn(v, v));
            }
        for (int c8 = 16; c8 < 32; ++c8)
            #pragma unroll
            for (int j = 0; j < 8; ++j) {
                float v = zrow[c8 * 8 + j];
                s2[j] = __fadd_rn(s2[j], __fmul_rn(v, v));
            }
        float b1 = __fadd_rn(__fadd_rn(__fadd_rn(s1[0], s1[1]), __fadd_rn(s1[2], s1[3])),
                             __fadd_rn(__fadd_rn(s1[4], s1[5]), __fadd_rn(s1[6], s1[7])));
        float b2 = __fadd_rn(__fadd_rn(__fadd_rn(s2[0], s2[1]), __fadd_rn(s2[2], s2[3])),
                             __fadd_rn(__fadd_rn(s2[4], s2[5]), __fadd_rn(s2[6], s2[7])));
        const float zzp = __fadd_rn(b1, b2);

        float bd = 3.4e38f; int bc = 0;
        #pragma unroll
        for (int h = 0; h < 2; ++h) {
            const int code = h * 256 + tid;
            const float4* crow4 = reinterpret_cast<const float4*>(cb + ((size_t)code << 8));
            float a0 = 0.f;
            for (int c4 = 0; c4 < 64; ++c4) {
                float4 cv = crow4[c4];
                a0 = __builtin_fmaf(zrow[c4 * 4 + 0], cv.x, a0);
                a0 = __builtin_fmaf(zrow[c4 * 4 + 1], cv.y, a0);
                a0 = __builtin_fmaf(zrow[c4 * 4 + 2], cv.z, a0);
                a0 = __builtin_fmaf(zrow[c4 * 4 + 3], cv.w, a0);
            }
            float d = __fadd_rn(__fsub_rn(zzp, __fmul_rn(2.0f, a0)), ccv[code]);
            if (d < bd) { bd = d; bc = code; }   // h ascending -> code ascending
        }
        sd[tid] = bd; sc[tid] = bc;
        __syncthreads();
        for (int off = 128; off > 0; off >>= 1) {
            if (tid < off) {
                float od = sd[tid + off]; int oc = sc[tid + off];
                if (od < sd[tid] || (od == sd[tid] && oc < sc[tid])) { sd[tid] = od; sc[tid] = oc; }
            }
            __syncthreads();
        }
        if (tid == 0) { out1f[pos] = (float)sc[0]; gapd[pos] = sd[0]; }
        __syncthreads();
    }
}

// ---------------------------------------------------------------------------
// Reduce: per-256-pos sums of d_min -> partials[256]
// ---------------------------------------------------------------------------
__global__ __launch_bounds__(256) void vq_reduce_kernel(
    const float* __restrict__ gapd, float* __restrict__ partials)
{
    const int t = threadIdx.x;
    __shared__ float s[256];
    s[t] = gapd[blockIdx.x * 256 + t];
    __syncthreads();
    for (int off = 128; off > 0; off >>= 1) {
        if (t < off) s[t] += s[t + off];
        __syncthreads();
    }
    if (t == 0) partials[blockIdx.x] = s[0];
}

// ---------------------------------------------------------------------------
// Gather: out0[b, c, hw] = cb[code][c], code read from out1 floats (proven)
// ---------------------------------------------------------------------------
__global__ __launch_bounds__(256) void vq_gather_kernel(
    const float* __restrict__ cb, const float* __restrict__ out1f,
    float* __restrict__ out0)
{
    const int blk = blockIdx.x;
    const int b   = blk >> 4;
    const int hw0 = (blk & 15) << 6;
    const int lane = threadIdx.x & 63;
    const int w    = threadIdx.x >> 6;

    __shared__ int sidx[64];
    if (threadIdx.x < 64) sidx[threadIdx.x] = (int)out1f[(blk << 6) + threadIdx.x];
    __syncthreads();

    const int code = sidx[lane];
    const float4* crow4 = reinterpret_cast<const float4*>(cb + ((size_t)code << 8) + (w << 6));
    float* ob = out0 + ((size_t)b << 18) + ((size_t)(w * 64) << 10) + hw0 + lane;
    #pragma unroll 4
    for (int j4 = 0; j4 < 16; ++j4) {
        float4 v = crow4[j4];
        ob[(size_t)(j4 * 4 + 0) << 10] = v.x;
        ob[(size_t)(j4 * 4 + 1) << 10] = v.y;
        ob[(size_t)(j4 * 4 + 2) << 10] = v.z;
        ob[(size_t)(j4 * 4 + 3) << 10] = v.w;
    }
}

// ---------------------------------------------------------------------------
// loss = 1.25 * sum(partials) / 2^24
// ---------------------------------------------------------------------------
__global__ __launch_bounds__(256) void vq_loss_kernel(
    const float* __restrict__ partials, float* __restrict__ out2)
{
    __shared__ float s[256];
    const int t = threadIdx.x;
    s[t] = partials[t];
    __syncthreads();
    for (int off = 128; off > 0; off >>= 1) {
        if (t < off) s[t] += s[t + off];
        __syncthreads();
    }
    if (t == 0)
        out2[0] = 1.25f * (s[0] * (1.0f / 16777216.0f));
}

// ---------------------------------------------------------------------------
extern "C" void kernel_launch(void* const* d_in, const int* in_sizes, int n_in,
                              void* d_out, int out_size, void* d_ws, size_t ws_size,
                              hipStream_t stream)
{
    const float* z  = (const float*)d_in[0];
    const float* cb = (const float*)d_in[1];

    float* out0 = (float*)d_out;
    float* out1 = out0 + OUT0_ELEMS;
    float* out2 = out1 + OUT1_ELEMS;

    // out0 scratch (dead before gather): Zh | Zl fill it exactly
    __hip_bfloat16* Zh = (__hip_bfloat16*)out0;             // 16.7M bf16
    __hip_bfloat16* Zl = (__hip_bfloat16*)(out0 + 8388608); // 16.7M bf16

    // ws (~772 KB, proven envelope):
    float* wsf      = (float*)d_ws;
    float* ccv      = wsf;                                   // 512
    float* partials = wsf + 512;                             // 256 (+pad)
    __hip_bfloat16* Ch = (__hip_bfloat16*)(wsf + 1024);      // 131072 bf16
    __hip_bfloat16* Cl = (__hip_bfloat16*)(wsf + 66560);     // 131072 bf16
    float* gapd     = wsf + 132096;                          // 65536 f32 (gap -> d_min)

    hipLaunchKernelGGL(vq_convcb_kernel,   dim3(512),  dim3(256), 0, stream, cb, Ch, Cl);
    hipLaunchKernelGGL(vq_cc_kernel,       dim3(2),    dim3(256), 0, stream, cb, ccv);
    hipLaunchKernelGGL(vq_splitz_kernel,   dim3(2048), dim3(256), 0, stream, z, Zh, Zl);
    hipLaunchKernelGGL(vq_screen_kernel,   dim3(1024), dim3(256), 0, stream,
                       Zh, Zl, Ch, Cl, ccv, out1, gapd);
    hipLaunchKernelGGL(vq_finalize_kernel, dim3(256),  dim3(256), 0, stream,
                       z, cb, ccv, out1, gapd);
    hipLaunchKernelGGL(vq_amb_kernel,      dim3(256),  dim3(256), 0, stream,
                       z, cb, ccv, out1, gapd);
    hipLaunchKernelGGL(vq_reduce_kernel,   dim3(256),  dim3(256), 0, stream, gapd, partials);
    hipLaunchKernelGGL(vq_gather_kernel,   dim3(1024), dim3(256), 0, stream, cb, out1, out0);
    hipLaunchKernelGGL(vq_loss_kernel,     dim3(1),    dim3(256), 0, stream, partials, out2);
}